// Round 2
// baseline (702.166 us; speedup 1.0000x reference)
//
#include <hip/hip_runtime.h>
#include <stdint.h>

#define N_PTS 524288
#define DQ 64
#define HQ 256
#define WQ 256
#define MAP_BYTES (2*DQ*HQ*WQ*4)   /* 33554432 */

typedef short bf8  __attribute__((ext_vector_type(8)));
typedef float f16v __attribute__((ext_vector_type(16)));

static __device__ __forceinline__ short f2bf(float f) {
    union { float f; uint32_t u; } v; v.f = f;
    return (short)((v.u + 0x7fffu + ((v.u >> 16) & 1u)) >> 16);
}

static __device__ __forceinline__ float fast_sigmoid(float x) {
    return 1.f / (1.f + __expf(-x));
}
static __device__ __forceinline__ float fast_tanh(float x) {
    return 1.f - 2.f / (__expf(2.f * x) + 1.f);
}

__global__ void k_scatter(const int* __restrict__ coors, int* __restrict__ map) {
    int i = blockIdx.x * 256 + threadIdx.x;
    int4 c = ((const int4*)coors)[i];                 // b,z,y,x
    map[((c.x*DQ + c.y)*HQ + c.z)*WQ + c.w] = i;
}

__global__ void k_feats(const float* __restrict__ xf, const float* __restrict__ hf,
                        short* __restrict__ fb) {
    int t = blockIdx.x * 256 + threadIdx.x;           // t < N*8
    int n = t >> 3, seg = t & 7;
    const float* src = (seg < 4) ? (xf + n*32 + seg*8) : (hf + n*32 + seg*8 - 32);
    float4 a = ((const float4*)src)[0];
    float4 b = ((const float4*)src)[1];
    bf8 r;
    r[0]=f2bf(a.x); r[1]=f2bf(a.y); r[2]=f2bf(a.z); r[3]=f2bf(a.w);
    r[4]=f2bf(b.x); r[5]=f2bf(b.y); r[6]=f2bf(b.z); r[7]=f2bf(b.w);
    ((bf8*)fb)[t] = r;
}

__global__ void k_wt(const float* __restrict__ w, short* __restrict__ wt) {
    int t = blockIdx.x * 256 + threadIdx.x;
    if (t >= 27*64*128) return;
    int jj = t & 7, c = (t >> 3) & 127, jg = (t >> 10) & 7, k = t >> 13;
    int j = jg*8 + jj;
    wt[t] = f2bf(w[(k*64 + j)*128 + c]);              // Wt[k][jg][c][jj] = W[k][j][c]
}

__launch_bounds__(256, 2)
__global__ void k_main(const int* __restrict__ map, const short* __restrict__ fb,
                       const short* __restrict__ wt, const float* __restrict__ bias,
                       const float* __restrict__ cfeat, const int* __restrict__ coors,
                       float* __restrict__ out)
{
    __shared__ short Alds[8*256*8];   // [jg][m 0..255][jj]  32 kB
    __shared__ short Wlds[8*128*8];   // [jg][c 0..127][jj]  16 kB

    const int tid  = threadIdx.x;
    const int lane = tid & 63;
    const int wv   = tid >> 6;
    const int l31  = lane & 31;
    const int lhi  = lane >> 5;

    const int pbase = blockIdx.x * 256;
    const int prow  = wv*64 + lane;       // this lane's gather row (block-local)
    const int p     = pbase + prow;

    const int4 cr = ((const int4*)coors)[p];   // b,z,y,x
    const int mbase = ((cr.x*DQ + cr.y)*HQ + cr.z)*WQ + cr.w;

    // ---- probe helper: offset index -> neighbor pid (or -1) ----
    auto probe = [&](int ko) -> int {
        int dz = ko/9 - 1, dy = (ko/3)%3 - 1, dxo = ko%3 - 1;
        if ((unsigned)(cr.y + dz) < (unsigned)DQ &&
            (unsigned)(cr.z + dy) < (unsigned)HQ &&
            (unsigned)(cr.w + dxo) < (unsigned)WQ)
            return map[mbase + (dz*HQ + dy)*WQ + dxo];
        return -1;
    };

    f16v acc[2][4];
    #pragma unroll
    for (int mt = 0; mt < 2; mt++)
        #pragma unroll
        for (int ct = 0; ct < 4; ct++) {
            float bv = bias[ct*32 + l31];
            #pragma unroll
            for (int r = 0; r < 16; r++) acc[mt][ct][r] = bv;
        }

    int4 ch[8];     // staged A row (gathered features for this lane's point)
    int4 wr[4];     // staged W slice chunk (this thread's share of 16 kB)

    auto gather = [&](int nid) {
        if (nid >= 0) {
            const int4* src = (const int4*)(fb + (size_t)nid*64);
            #pragma unroll
            for (int g = 0; g < 8; g++) ch[g] = src[g];
        } else {
            #pragma unroll
            for (int g = 0; g < 8; g++) ch[g] = make_int4(0,0,0,0);
        }
    };
    auto wload = [&](int ko) {
        const int4* wsrc = (const int4*)(wt + ko*8192);
        #pragma unroll
        for (int i = 0; i < 4; i++) wr[i] = wsrc[i*256 + tid];
    };

    // ---- prologue: prime the pipeline ----
    int n0   = probe(0);
    int nidg = probe(1);     // row to gather during iter 0 (for iter 1)
    gather(n0);              // A data for iter 0
    wload(0);                // W data for iter 0
    int nidp = -1;

    #pragma unroll 1
    for (int ko = 0; ko < 27; ko++) {
        __syncthreads();   // all waves done reading LDS of previous iter

        // ---- reg -> LDS (only LDS ops between the barriers) ----
        {
            int4* ad = (int4*)Alds;
            #pragma unroll
            for (int g = 0; g < 8; g++) ad[g*256 + prow] = ch[g];
            int4* wd = (int4*)Wlds;
            #pragma unroll
            for (int i = 0; i < 4; i++) wd[i*256 + tid] = wr[i];
        }

        __syncthreads();

        // ---- issue next iteration's global traffic (overlaps MFMA below) ----
        if (ko < 26) {
            gather(nidg);        // features for iter ko+1
            wload(ko + 1);       // weights  for iter ko+1
        }
        if (ko < 25) nidp = probe(ko + 2);   // nid for gather at iter ko+1

        // ---- MFMA: wave owns rows [wv*64, wv*64+64), all 128 cols ----
        #pragma unroll
        for (int ks = 0; ks < 4; ks++) {
            int jg = ks*2 + lhi;
            bf8 a0 = *(const bf8*)&Alds[(jg*256 + wv*64 +      l31)*8];
            bf8 a1 = *(const bf8*)&Alds[(jg*256 + wv*64 + 32 + l31)*8];
            #pragma unroll
            for (int ct = 0; ct < 4; ct++) {
                bf8 b = *(const bf8*)&Wlds[(jg*128 + ct*32 + l31)*8];
                acc[0][ct] = __builtin_amdgcn_mfma_f32_32x32x16_bf16(a0, b, acc[0][ct], 0, 0, 0);
                acc[1][ct] = __builtin_amdgcn_mfma_f32_32x32x16_bf16(a1, b, acc[1][ct], 0, 0, 0);
            }
        }

        nidg = nidp;
    }

    // ---- epilogue: LSTM gates, lane-local ----
    #pragma unroll
    for (int mt = 0; mt < 2; mt++) {
        #pragma unroll
        for (int r = 0; r < 16; r++) {
            int row = (r & 3) + 8*(r >> 2) + 4*lhi;
            int pp  = pbase + wv*64 + mt*32 + row;
            float gi = acc[mt][0][r];
            float gf = acc[mt][1][r];
            float go = acc[mt][2][r];
            float gg = acc[mt][3][r];
            float cv = cfeat[pp*32 + l31];
            float si = fast_sigmoid(gi);
            float sf = fast_sigmoid(gf);
            float so = fast_sigmoid(go);
            float tg = fast_tanh(gg);
            float cn = sf*cv + si*tg;
            float hn = so * fast_tanh(cn);
            out[pp*32 + l31] = hn;
            out[N_PTS*32 + pp*32 + l31] = cn;
        }
    }
}

extern "C" void kernel_launch(void* const* d_in, const int* in_sizes, int n_in,
                              void* d_out, int out_size, void* d_ws, size_t ws_size,
                              hipStream_t stream) {
    const float* xf    = (const float*)d_in[0];
    const float* hf    = (const float*)d_in[1];
    const float* cf    = (const float*)d_in[2];
    const float* w     = (const float*)d_in[3];
    const float* bias  = (const float*)d_in[4];
    const int*   coors = (const int*)d_in[5];
    float* out = (float*)d_out;

    int*   map = (int*)d_ws;
    short* fb  = (short*)((char*)d_ws + MAP_BYTES);
    short* wtb = (short*)((char*)d_ws + MAP_BYTES + (size_t)N_PTS*64*2);

    hipMemsetAsync(map, 0xFF, MAP_BYTES, stream);                       // map = -1
    k_scatter<<<N_PTS/256, 256, 0, stream>>>(coors, map);
    k_feats<<<(N_PTS*8)/256, 256, 0, stream>>>(xf, hf, fb);
    k_wt<<<(27*64*128 + 255)/256, 256, 0, stream>>>(w, wtb);
    k_main<<<N_PTS/256, 256, 0, stream>>>(map, fb, wtb, bias, cf, coors, out);
}

// Round 3
// 503.065 us; speedup vs baseline: 1.3958x; 1.3958x over previous
//
#include <hip/hip_runtime.h>
#include <stdint.h>

#define N_PTS 524288
#define DQ 64
#define HQ 256
#define WQ 256
#define MAP_BYTES (2*DQ*HQ*WQ*4)   /* 33554432 */

typedef short bf8  __attribute__((ext_vector_type(8)));
typedef float f16v __attribute__((ext_vector_type(16)));

static __device__ __forceinline__ short f2bf(float f) {
    union { float f; uint32_t u; } v; v.f = f;
    return (short)((v.u + 0x7fffu + ((v.u >> 16) & 1u)) >> 16);
}
static __device__ __forceinline__ float fast_sigmoid(float x) {
    return 1.f / (1.f + __expf(-x));
}
static __device__ __forceinline__ float fast_tanh(float x) {
    return 1.f - 2.f / (__expf(2.f * x) + 1.f);
}

// fused: bf16 feature pack + coordinate scatter
__global__ void k_feats(const float* __restrict__ xf, const float* __restrict__ hf,
                        const int* __restrict__ coors, short* __restrict__ fb,
                        int* __restrict__ map) {
    int t = blockIdx.x * 256 + threadIdx.x;           // t < N*8
    int n = t >> 3, seg = t & 7;
    const float* src = (seg < 4) ? (xf + n*32 + seg*8) : (hf + n*32 + seg*8 - 32);
    float4 a = ((const float4*)src)[0];
    float4 b = ((const float4*)src)[1];
    bf8 r;
    r[0]=f2bf(a.x); r[1]=f2bf(a.y); r[2]=f2bf(a.z); r[3]=f2bf(a.w);
    r[4]=f2bf(b.x); r[5]=f2bf(b.y); r[6]=f2bf(b.z); r[7]=f2bf(b.w);
    ((bf8*)fb)[t] = r;
    if (seg == 0) {
        int4 c = ((const int4*)coors)[n];
        map[((c.x*DQ + c.y)*HQ + c.z)*WQ + c.w] = n;
    }
}

__global__ void k_wt(const float* __restrict__ w, short* __restrict__ wt) {
    int t = blockIdx.x * 256 + threadIdx.x;
    if (t >= 27*64*128) return;
    int jj = t & 7, c = (t >> 3) & 127, jg = (t >> 10) & 7, k = t >> 13;
    int j = jg*8 + jj;
    wt[t] = f2bf(w[(k*64 + j)*128 + c]);              // Wt[k][jg][c][jj] = W[k][j][c]
}

__launch_bounds__(256, 2)
__global__ void k_main(const int* __restrict__ map, const short* __restrict__ fb,
                       const short* __restrict__ wt, const float* __restrict__ bias,
                       const float* __restrict__ cfeat, const int* __restrict__ coors,
                       const short* __restrict__ zp, float* __restrict__ out)
{
    __shared__ short Wlds[2][8192];   // double-buffered W slice: 2 x 16 kB

    const int tid  = threadIdx.x;
    const int lane = tid & 63;
    const int wv   = tid >> 6;
    const int l31  = lane & 31;
    const int lhi  = lane >> 5;

    const int pbase = blockIdx.x * 256;
    const int p     = pbase + wv*64 + lane;

    const int4 cr = ((const int4*)coors)[p];   // b,z,y,x
    const int mbase = ((cr.x*DQ + cr.y)*HQ + cr.z)*WQ + cr.w;

    auto probe = [&](int ko) -> int {
        int dz = ko/9 - 1, dy = (ko/3)%3 - 1, dxo = ko%3 - 1;
        if ((unsigned)(cr.y + dz) < (unsigned)DQ &&
            (unsigned)(cr.z + dy) < (unsigned)HQ &&
            (unsigned)(cr.w + dxo) < (unsigned)WQ)
            return map[mbase + (dz*HQ + dy)*WQ + dxo];
        return -1;
    };

    // async stage of W[ko] (16 kB) into Wlds[ko&1]; no VGPR staging
    auto stageW = [&](int ko) {
        const short* src = wt + ko*8192;
        #pragma unroll
        for (int i = 0; i < 4; i++) {
            int cb = i*256 + wv*64;          // 16B-chunk base for this wave
            __builtin_amdgcn_global_load_lds(
                (const __attribute__((address_space(1))) void*)(src + (size_t)(cb + lane)*8),
                (__attribute__((address_space(3))) void*)&Wlds[ko & 1][cb*8],
                16, 0, 0);
        }
    };

    // direct register gather of this lane's A fragments for one offset:
    // dst[j]   = row n0 chunk (2j+lhi), dst[4+j] = row n1 chunk (2j+lhi)
    auto gather = [&](int n0, int n1, bf8* dst) {
        const short* s0 = (n0 >= 0) ? (fb + (size_t)n0*64 + lhi*8) : (zp + lhi*8);
        const short* s1 = (n1 >= 0) ? (fb + (size_t)n1*64 + lhi*8) : (zp + lhi*8);
        #pragma unroll
        for (int j = 0; j < 4; j++) {
            dst[j]     = *(const bf8*)(s0 + j*16);
            dst[4 + j] = *(const bf8*)(s1 + j*16);
        }
    };

    f16v acc[2][4];
    #pragma unroll
    for (int mt = 0; mt < 2; mt++)
        #pragma unroll
        for (int ct = 0; ct < 4; ct++) {
            float bv = bias[ct*32 + l31];
            #pragma unroll
            for (int r = 0; r < 16; r++) acc[mt][ct][r] = bv;
        }

    // ---- prologue: prime probes, first gathers, W(0) ----
    int pA = probe(0);
    int pB = probe(1);
    int pr_old = probe(2);
    stageW(0);

    bf8 a_cur[8], a_next[8];
    {
        int g0 = __shfl(pA, l31, 64);
        int g1 = __shfl(pA, l31 + 32, 64);
        gather(g0, g1, a_cur);
    }
    int g0n = __shfl(pB, l31, 64);
    int g1n = __shfl(pB, l31 + 32, 64);

    #pragma unroll 1
    for (int ko = 0; ko < 27; ko++) {
        __syncthreads();   // W[ko&1] complete (barrier drains each wave's W DMA)

        if (ko < 26) {
            stageW(ko + 1);              // oldest vmem ops -> drained at next barrier
            gather(g0n, g1n, a_next);    // plain loads, used next iter
        }
        int pr_new = (ko < 24) ? probe(ko + 3) : -1;

        // ---- MFMA phase: a from regs, b from LDS ----
        const int buf = ko & 1;
        #pragma unroll
        for (int ks = 0; ks < 4; ks++) {
            int jg = ks*2 + lhi;
            const short* wb = &Wlds[buf][(jg*128 + l31)*8];
            #pragma unroll
            for (int ct = 0; ct < 4; ct++) {
                bf8 b = *(const bf8*)(wb + ct*32*8);
                acc[0][ct] = __builtin_amdgcn_mfma_f32_32x32x16_bf16(a_cur[ks],     b, acc[0][ct], 0, 0, 0);
                acc[1][ct] = __builtin_amdgcn_mfma_f32_32x32x16_bf16(a_cur[4 + ks], b, acc[1][ct], 0, 0, 0);
            }
        }

        if (ko < 25) {                    // nids for data (ko+2), used next iter
            g0n = __shfl(pr_old, l31, 64);
            g1n = __shfl(pr_old, l31 + 32, 64);
            pr_old = pr_new;
        }
        #pragma unroll
        for (int j = 0; j < 8; j++) a_cur[j] = a_next[j];
    }

    // ---- epilogue: LSTM gates, lane-local ----
    #pragma unroll
    for (int mt = 0; mt < 2; mt++) {
        #pragma unroll
        for (int r = 0; r < 16; r++) {
            int row = (r & 3) + 8*(r >> 2) + 4*lhi;
            int pp  = pbase + wv*64 + mt*32 + row;
            float gi = acc[mt][0][r];
            float gf = acc[mt][1][r];
            float go = acc[mt][2][r];
            float gg = acc[mt][3][r];
            float cv = cfeat[pp*32 + l31];
            float si = fast_sigmoid(gi);
            float sf = fast_sigmoid(gf);
            float so = fast_sigmoid(go);
            float tg = fast_tanh(gg);
            float cn = sf*cv + si*tg;
            float hn = so * fast_tanh(cn);
            out[pp*32 + l31] = hn;
            out[N_PTS*32 + pp*32 + l31] = cn;
        }
    }
}

extern "C" void kernel_launch(void* const* d_in, const int* in_sizes, int n_in,
                              void* d_out, int out_size, void* d_ws, size_t ws_size,
                              hipStream_t stream) {
    const float* xf    = (const float*)d_in[0];
    const float* hf    = (const float*)d_in[1];
    const float* cf    = (const float*)d_in[2];
    const float* w     = (const float*)d_in[3];
    const float* bias  = (const float*)d_in[4];
    const int*   coors = (const int*)d_in[5];
    float* out = (float*)d_out;

    int*   map = (int*)d_ws;
    short* fb  = (short*)((char*)d_ws + MAP_BYTES);
    short* wtb = (short*)((char*)d_ws + MAP_BYTES + (size_t)N_PTS*64*2);
    short* zp  = (short*)((char*)d_ws + MAP_BYTES + (size_t)N_PTS*64*2 + 27*64*128*2);

    hipMemsetAsync(map, 0xFF, MAP_BYTES, stream);                       // map = -1
    hipMemsetAsync(zp, 0, 256, stream);                                 // zero row
    k_feats<<<(N_PTS*8)/256, 256, 0, stream>>>(xf, hf, coors, fb, map);
    k_wt<<<(27*64*128 + 255)/256, 256, 0, stream>>>(w, wtb);
    k_main<<<N_PTS/256, 256, 0, stream>>>(map, fb, wtb, bias, cf, coors, zp, out);
}